// Round 1
// baseline (207.566 us; speedup 1.0000x reference)
//
#include <hip/hip_runtime.h>

// B=4, S=1024, E=1024, H=16, D=64.  All MFMA in bf16 (16x16x32), fp32 accum.

typedef unsigned short u16;
using s16x8 = __attribute__((ext_vector_type(8))) short;   // 8 bf16 = 4 VGPR
using f32x4 = __attribute__((ext_vector_type(4))) float;   // MFMA C/D
using u16x4 = __attribute__((ext_vector_type(4))) unsigned short;

#define AS1 __attribute__((address_space(1)))
#define AS3 __attribute__((address_space(3)))

#define L2E 1.44269504088896f

__device__ __forceinline__ u16 f2bf(float f) {
    unsigned u = __float_as_uint(f);
    u += 0x7fffu + ((u >> 16) & 1u);   // RTN-even
    return (u16)(u >> 16);
}

// ---------------- fp32 -> bf16 convert ----------------
__global__ void k_cvt(const float* __restrict__ src, u16* __restrict__ dst, int n4) {
    int i = blockIdx.x * blockDim.x + threadIdx.x;
    if (i >= n4) return;
    float4 v = reinterpret_cast<const float4*>(src)[i];
    u16x4 o = { f2bf(v.x), f2bf(v.y), f2bf(v.z), f2bf(v.w) };
    reinterpret_cast<u16x4*>(dst)[i] = o;
}

// ---------------- init context_vector with out_proj_bias ----------------
__global__ void k_init_ctxvec(const float* __restrict__ bias, float* __restrict__ out) {
    int i = blockIdx.x * blockDim.x + threadIdx.x;
    if (i < 4096) out[i] = bias[i & 1023];
}

// ---------------- 128x128 BT GEMM (m97 structure): C = A * B^T ----------------
// A: [M][1024] bf16, B: [N][1024] bf16 (both K-major).
// MEAN_OUT=false: C_bf16[m][N_DIM] = acc + bias[n]
// MEAN_OUT=true : atomicAdd(outvec[b*1024+n], colsum/1024), b = m0/1024
template<int N_DIM, bool MEAN_OUT>
__global__ __launch_bounds__(256) void k_gemm_bt(
    const u16* __restrict__ A, const u16* __restrict__ B,
    const float* __restrict__ bias, u16* __restrict__ C, float* __restrict__ outvec) {
    const int K = 1024;
    const int n0 = blockIdx.x * 128, m0 = blockIdx.y * 128;
    const int tid = threadIdx.x, lane = tid & 63, w = tid >> 6;
    const int wm = w >> 1, wn = w & 1;
    __shared__ __attribute__((aligned(16))) u16 As[128 * 64];
    __shared__ __attribute__((aligned(16))) u16 Bs[128 * 64];

    f32x4 acc[4][4];
    #pragma unroll
    for (int mi = 0; mi < 4; ++mi)
        #pragma unroll
        for (int nj = 0; nj < 4; ++nj) acc[mi][nj] = (f32x4){0.f, 0.f, 0.f, 0.f};

    for (int k0 = 0; k0 < K; k0 += 64) {
        #pragma unroll
        for (int r = 0; r < 4; ++r) {          // 1024 16B chunks per tile, 4/thread
            int c = tid + r * 256;
            int row = c >> 3, j = c & 7;
            __builtin_amdgcn_global_load_lds(
                (AS1 const void*)(A + (size_t)(m0 + row) * K + k0 + j * 8),
                (AS3 void*)(&As[c * 8]), 16, 0, 0);
            __builtin_amdgcn_global_load_lds(
                (AS1 const void*)(B + (size_t)(n0 + row) * K + k0 + j * 8),
                (AS3 void*)(&Bs[c * 8]), 16, 0, 0);
        }
        __syncthreads();                        // drains vmcnt
        #pragma unroll
        for (int kk = 0; kk < 64; kk += 32) {
            s16x8 av[4], bv[4];
            #pragma unroll
            for (int mi = 0; mi < 4; ++mi)
                av[mi] = *reinterpret_cast<const s16x8*>(
                    &As[(wm * 64 + mi * 16 + (lane & 15)) * 64 + kk + (lane >> 4) * 8]);
            #pragma unroll
            for (int nj = 0; nj < 4; ++nj)
                bv[nj] = *reinterpret_cast<const s16x8*>(
                    &Bs[(wn * 64 + nj * 16 + (lane & 15)) * 64 + kk + (lane >> 4) * 8]);
            #pragma unroll
            for (int mi = 0; mi < 4; ++mi)
                #pragma unroll
                for (int nj = 0; nj < 4; ++nj)
                    acc[mi][nj] = __builtin_amdgcn_mfma_f32_16x16x32_bf16(av[mi], bv[nj], acc[mi][nj], 0, 0, 0);
        }
        __syncthreads();
    }

    if constexpr (!MEAN_OUT) {
        #pragma unroll
        for (int nj = 0; nj < 4; ++nj) {
            int n = n0 + wn * 64 + nj * 16 + (lane & 15);
            float bvs = bias[n];
            #pragma unroll
            for (int mi = 0; mi < 4; ++mi)
                #pragma unroll
                for (int i = 0; i < 4; ++i) {
                    int m = m0 + wm * 64 + mi * 16 + (lane >> 4) * 4 + i;
                    C[(size_t)m * N_DIM + n] = f2bf(acc[mi][nj][i] + bvs);
                }
        }
    } else {
        int b = m0 >> 10;
        #pragma unroll
        for (int nj = 0; nj < 4; ++nj) {
            float s = 0.f;
            #pragma unroll
            for (int mi = 0; mi < 4; ++mi)
                #pragma unroll
                for (int i = 0; i < 4; ++i) s += acc[mi][nj][i];
            s += __shfl_xor(s, 16);
            s += __shfl_xor(s, 32);
            if ((lane >> 4) == 0) {
                int n = n0 + wn * 64 + nj * 16 + (lane & 15);
                atomicAdd(&outvec[b * 1024 + n], s * (1.0f / 1024.0f));
            }
        }
    }
}

// ---------------- flash attention: per (b, h, 64-row q-tile) ----------------
// qkv: [4096][3072] bf16 (Q|K|V). Writes ctx bf16 [4096][1024] and (m,l) per row.
__global__ __launch_bounds__(256) void k_flash(const u16* __restrict__ qkv,
                                               u16* __restrict__ ctx,
                                               float2* __restrict__ ml) {
    const int qt = blockIdx.x, h = blockIdx.y, b = blockIdx.z;
    const int q0 = qt * 64;
    const int tid = threadIdx.x, lane = tid & 63, w = tid >> 6;
    __shared__ __attribute__((aligned(16))) u16 Qs[64 * 64];
    __shared__ __attribute__((aligned(16))) u16 Ks[64 * 64];
    __shared__ __attribute__((aligned(16))) u16 Vt[64 * 64];   // [d][t], chunk-XOR swizzled
    __shared__ __attribute__((aligned(16))) u16 Ps[4][16 * 64];

    // stage Q (XOR-swizzled rows)
    #pragma unroll
    for (int r = 0; r < 2; ++r) {
        int c = tid + r * 256;
        int row = c >> 3, j = c & 7;
        *reinterpret_cast<s16x8*>(&Qs[row * 64 + ((j ^ (row & 7)) * 8)]) =
            *reinterpret_cast<const s16x8*>(qkv + (size_t)(b * 1024 + q0 + row) * 3072 + h * 64 + j * 8);
    }

    f32x4 ctxa[4];
    #pragma unroll
    for (int nj = 0; nj < 4; ++nj) ctxa[nj] = (f32x4){0.f, 0.f, 0.f, 0.f};
    float m_i[4], l_i[4];
    #pragma unroll
    for (int i = 0; i < 4; ++i) { m_i[i] = -3.0e38f; l_i[i] = 0.f; }

    for (int kt = 0; kt < 16; ++kt) {
        int t0 = kt * 64;
        // stage K row-major swizzled
        #pragma unroll
        for (int r = 0; r < 2; ++r) {
            int c = tid + r * 256;
            int row = c >> 3, j = c & 7;
            *reinterpret_cast<s16x8*>(&Ks[row * 64 + ((j ^ (row & 7)) * 8)]) =
                *reinterpret_cast<const s16x8*>(qkv + (size_t)(b * 1024 + t0 + row) * 3072 + 1024 + h * 64 + j * 8);
        }
        // stage V transposed: Vt[d][t], physical chunk = (t>>3) ^ (d&7)
        #pragma unroll
        for (int it = 0; it < 8; ++it) {
            int d = (lane & 15) + 16 * w;
            int t = 2 * (lane >> 4) + 8 * it;
            const u16* vsrc = qkv + (size_t)(b * 1024 + t0 + t) * 3072 + 2048 + h * 64 + d;
            unsigned pk = (unsigned)vsrc[0] | ((unsigned)vsrc[3072] << 16);
            *reinterpret_cast<unsigned*>(&Vt[d * 64 + (((t >> 3) ^ (d & 7)) * 8) + (t & 7)]) = pk;
        }
        __syncthreads();

        // QK^T for this wave's 16 q-rows x 64 t
        f32x4 sc[4];
        #pragma unroll
        for (int tj = 0; tj < 4; ++tj) sc[tj] = (f32x4){0.f, 0.f, 0.f, 0.f};
        #pragma unroll
        for (int kk = 0; kk < 64; kk += 32) {
            int qrow = w * 16 + (lane & 15);
            s16x8 qa = *reinterpret_cast<const s16x8*>(
                &Qs[qrow * 64 + ((((kk >> 3) + (lane >> 4)) ^ (qrow & 7)) * 8)]);
            #pragma unroll
            for (int tj = 0; tj < 4; ++tj) {
                int trow = tj * 16 + (lane & 15);
                s16x8 kb = *reinterpret_cast<const s16x8*>(
                    &Ks[trow * 64 + ((((kk >> 3) + (lane >> 4)) ^ (trow & 7)) * 8)]);
                sc[tj] = __builtin_amdgcn_mfma_f32_16x16x32_bf16(qa, kb, sc[tj], 0, 0, 0);
            }
        }
        #pragma unroll
        for (int tj = 0; tj < 4; ++tj) sc[tj] = sc[tj] * 0.125f;   // 1/sqrt(64)

        // online softmax: lane's rows are (lane>>4)*4 + i
        #pragma unroll
        for (int i = 0; i < 4; ++i) {
            float mx = fmaxf(fmaxf(sc[0][i], sc[1][i]), fmaxf(sc[2][i], sc[3][i]));
            #pragma unroll
            for (int off = 1; off < 16; off <<= 1) mx = fmaxf(mx, __shfl_xor(mx, off));
            float mnew = fmaxf(m_i[i], mx);
            float fs = exp2f((m_i[i] - mnew) * L2E);
            m_i[i] = mnew;
            float rs = 0.f;
            #pragma unroll
            for (int tj = 0; tj < 4; ++tj) {
                float p = exp2f((sc[tj][i] - mnew) * L2E);
                sc[tj][i] = p;
                rs += p;
            }
            #pragma unroll
            for (int off = 1; off < 16; off <<= 1) rs += __shfl_xor(rs, off);
            l_i[i] = l_i[i] * fs + rs;
            #pragma unroll
            for (int nj = 0; nj < 4; ++nj) ctxa[nj][i] *= fs;
        }

        // P -> LDS bf16 (per-wave buffer, swizzled like K)
        #pragma unroll
        for (int i = 0; i < 4; ++i) {
            int prow = (lane >> 4) * 4 + i;
            #pragma unroll
            for (int tj = 0; tj < 4; ++tj) {
                int t = tj * 16 + (lane & 15);
                Ps[w][prow * 64 + (((t >> 3) ^ (prow & 7)) * 8) + (t & 7)] = f2bf(sc[tj][i]);
            }
        }
        // PV: A = P (rows=q), B = Vt rows (col=d, k=t contiguous).  In-wave LDS RAW is in-order.
        #pragma unroll
        for (int kk = 0; kk < 64; kk += 32) {
            int prow = lane & 15;
            s16x8 pa = *reinterpret_cast<const s16x8*>(
                &Ps[w][prow * 64 + ((((kk >> 3) + (lane >> 4)) ^ (prow & 7)) * 8)]);
            #pragma unroll
            for (int nj = 0; nj < 4; ++nj) {
                int d = nj * 16 + (lane & 15);
                s16x8 vb = *reinterpret_cast<const s16x8*>(
                    &Vt[d * 64 + ((((kk >> 3) + (lane >> 4)) ^ (d & 7)) * 8)]);
                ctxa[nj] = __builtin_amdgcn_mfma_f32_16x16x32_bf16(pa, vb, ctxa[nj], 0, 0, 0);
            }
        }
        __syncthreads();
    }

    #pragma unroll
    for (int i = 0; i < 4; ++i) {
        float invl = 1.0f / l_i[i];
        int row = q0 + w * 16 + (lane >> 4) * 4 + i;
        #pragma unroll
        for (int nj = 0; nj < 4; ++nj) {
            int d = nj * 16 + (lane & 15);
            ctx[(size_t)(b * 1024 + row) * 1024 + h * 64 + d] = f2bf(ctxa[nj][i] * invl);
        }
        if ((lane & 15) == 0)
            ml[(size_t)(b * 16 + h) * 1024 + row] = make_float2(m_i[i], l_i[i]);
    }
}

// ---------------- attn_weights = mean over heads of softmax(QK^T) ----------------
// per (b, 64-row s-tile, 64-col t-tile): loop heads, recompute scores, normalize via (m,l)
__global__ __launch_bounds__(256) void k_attnw(const u16* __restrict__ qkv,
                                               const float2* __restrict__ ml,
                                               float* __restrict__ attnw) {
    const int tt = blockIdx.x, st = blockIdx.y, b = blockIdx.z;
    const int s0 = st * 64, t0 = tt * 64;
    const int tid = threadIdx.x, lane = tid & 63, w = tid >> 6;
    __shared__ __attribute__((aligned(16))) u16 Qs[64 * 64];
    __shared__ __attribute__((aligned(16))) u16 Ks[64 * 64];
    __shared__ float2 mls[16][64];

    #pragma unroll
    for (int r = 0; r < 4; ++r) {
        int idx = tid + r * 256;
        int hh = idx >> 6, row = idx & 63;
        mls[hh][row] = ml[(size_t)(b * 16 + hh) * 1024 + s0 + row];
    }

    f32x4 acc[4];
    #pragma unroll
    for (int tj = 0; tj < 4; ++tj) acc[tj] = (f32x4){0.f, 0.f, 0.f, 0.f};

    for (int h = 0; h < 16; ++h) {
        __syncthreads();   // also covers mls staging on first iter
        #pragma unroll
        for (int r = 0; r < 2; ++r) {
            int c = tid + r * 256;
            int row = c >> 3, j = c & 7;
            *reinterpret_cast<s16x8*>(&Qs[row * 64 + ((j ^ (row & 7)) * 8)]) =
                *reinterpret_cast<const s16x8*>(qkv + (size_t)(b * 1024 + s0 + row) * 3072 + h * 64 + j * 8);
            *reinterpret_cast<s16x8*>(&Ks[row * 64 + ((j ^ (row & 7)) * 8)]) =
                *reinterpret_cast<const s16x8*>(qkv + (size_t)(b * 1024 + t0 + row) * 3072 + 1024 + h * 64 + j * 8);
        }
        __syncthreads();

        f32x4 sc[4];
        #pragma unroll
        for (int tj = 0; tj < 4; ++tj) sc[tj] = (f32x4){0.f, 0.f, 0.f, 0.f};
        #pragma unroll
        for (int kk = 0; kk < 64; kk += 32) {
            int qrow = w * 16 + (lane & 15);
            s16x8 qa = *reinterpret_cast<const s16x8*>(
                &Qs[qrow * 64 + ((((kk >> 3) + (lane >> 4)) ^ (qrow & 7)) * 8)]);
            #pragma unroll
            for (int tj = 0; tj < 4; ++tj) {
                int trow = tj * 16 + (lane & 15);
                s16x8 kb = *reinterpret_cast<const s16x8*>(
                    &Ks[trow * 64 + ((((kk >> 3) + (lane >> 4)) ^ (trow & 7)) * 8)]);
                sc[tj] = __builtin_amdgcn_mfma_f32_16x16x32_bf16(qa, kb, sc[tj], 0, 0, 0);
            }
        }
        #pragma unroll
        for (int i = 0; i < 4; ++i) {
            int row = w * 16 + (lane >> 4) * 4 + i;
            float2 M = mls[h][row];
            float invl = 1.0f / M.y;
            #pragma unroll
            for (int tj = 0; tj < 4; ++tj)
                acc[tj][i] += exp2f((sc[tj][i] * 0.125f - M.x) * L2E) * invl;
        }
    }

    #pragma unroll
    for (int i = 0; i < 4; ++i) {
        int row = s0 + w * 16 + (lane >> 4) * 4 + i;
        #pragma unroll
        for (int tj = 0; tj < 4; ++tj)
            attnw[(size_t)(b * 1024 + row) * 1024 + t0 + tj * 16 + (lane & 15)] = acc[tj][i] * 0.0625f;
    }
}

// ---------------- launch ----------------
extern "C" void kernel_launch(void* const* d_in, const int* in_sizes, int n_in,
                              void* d_out, int out_size, void* d_ws, size_t ws_size,
                              hipStream_t stream) {
    const float* lstm = (const float*)d_in[0];   // [4,1024,1024]
    const float* wqkv = (const float*)d_in[1];   // [3072,1024]
    const float* bqkv = (const float*)d_in[2];   // [3072]
    const float* wout = (const float*)d_in[3];   // [1024,1024]
    const float* bout = (const float*)d_in[4];   // [1024]
    float* out = (float*)d_out;                  // [4096 ctxvec | 4*1024*1024 attn]

    char* ws = (char*)d_ws;
    u16*    Xbf   = (u16*)(ws);                          // 8 MiB
    u16*    Wqkvb = (u16*)(ws + 8u  * 1024 * 1024);      // 6 MiB
    u16*    Woutb = (u16*)(ws + 14u * 1024 * 1024);      // 2 MiB
    u16*    qkv   = (u16*)(ws + 16u * 1024 * 1024);      // 24 MiB
    u16*    ctx   = (u16*)(ws + 40u * 1024 * 1024);      // 8 MiB
    float2* ml    = (float2*)(ws + 48u * 1024 * 1024);   // 0.5 MiB

    k_cvt<<<4096, 256, 0, stream>>>(lstm, Xbf, 4096 * 1024 / 4);
    k_cvt<<<3072, 256, 0, stream>>>(wqkv, Wqkvb, 3072 * 1024 / 4);
    k_cvt<<<1024, 256, 0, stream>>>(wout, Woutb, 1024 * 1024 / 4);
    k_init_ctxvec<<<16, 256, 0, stream>>>(bout, out);

    k_gemm_bt<3072, false><<<dim3(24, 32), 256, 0, stream>>>(Xbf, Wqkvb, bqkv, qkv, nullptr);
    k_flash<<<dim3(16, 16, 4), 256, 0, stream>>>(qkv, ctx, ml);
    k_attnw<<<dim3(16, 16, 4), 256, 0, stream>>>(qkv, ml, out + 4096);
    k_gemm_bt<1024, true><<<dim3(8, 32), 256, 0, stream>>>(ctx, Woutb, nullptr, nullptr, out);
}